// Round 4
// baseline (172.096 us; speedup 1.0000x reference)
//
#include <hip/hip_runtime.h>

typedef __attribute__((ext_vector_type(8))) short short8;
typedef __attribute__((ext_vector_type(4))) float float4_t;

#define MFMA16(A, B, C) __builtin_amdgcn_mfma_f32_16x16x32_bf16(A, B, C, 0, 0, 0)

__device__ __forceinline__ unsigned short f2bf(float f) {
  unsigned int u = __builtin_bit_cast(unsigned int, f);
  u += 0x7FFFu + ((u >> 16) & 1u);   // RNE
  return (unsigned short)(u >> 16);
}

// ---------------- conversion kernels ----------------
__global__ void cvt_f32_bf16(const float* __restrict__ in,
                             unsigned short* __restrict__ out, int n4) {
  int i = blockIdx.x * blockDim.x + threadIdx.x;
  if (i >= n4) return;
  float4 v = reinterpret_cast<const float4*>(in)[i];
  ushort4 r;
  r.x = f2bf(v.x); r.y = f2bf(v.y); r.z = f2bf(v.z); r.w = f2bf(v.w);
  reinterpret_cast<ushort4*>(out)[i] = r;
}

// w: D x E row-major -> wT: E x D row-major (bf16)
__global__ void cvt_transpose(const float* __restrict__ w,
                              unsigned short* __restrict__ wT, int D, int E) {
  int idx = blockIdx.x * blockDim.x + threadIdx.x;
  if (idx >= D * E) return;
  int e = idx / D, d = idx - e * D;
  wT[idx] = f2bf(w[d * E + e]);
}

// ---------------- QKV GEMM: (16384x384) @ (384x1152) + bias ----------------
// Scatter epilogue: q (pre-scaled by 0.125, exact in bf16) -> (B,H,N,hd),
// k -> (B,H,N,hd), v -> (B,H,hd,N) with key index PERMUTED within each
// 32-block: pos = 2*(n&15) | ((n>>4)&1), matching attn's packed-P layout.
__global__ __launch_bounds__(256) void gemm_qkv(
    const unsigned short* __restrict__ xb,
    const unsigned short* __restrict__ wT,
    const float* __restrict__ bias,
    unsigned short* __restrict__ qb,
    unsigned short* __restrict__ kb,
    unsigned short* __restrict__ vt) {
  __shared__ alignas(16) unsigned short As[128][72];
  __shared__ alignas(16) unsigned short Bs[128][72];
  const int bm = blockIdx.x / 9, bn = blockIdx.x % 9;
  const int m0 = bm * 128, n0 = bn * 128;
  const int lane = threadIdx.x & 63, wid = threadIdx.x >> 6;
  const int lr = lane & 15, lg = lane >> 4;
  const int wm = wid >> 1, wn = wid & 1;
  float4_t acc[4][4] = {};

  for (int k0 = 0; k0 < 384; k0 += 64) {
    __syncthreads();
#pragma unroll
    for (int i = 0; i < 4; ++i) {
      int idx = threadIdx.x + i * 256;
      int r = idx >> 3, c = (idx & 7) * 8;
      *reinterpret_cast<short8*>(&As[r][c]) =
          *reinterpret_cast<const short8*>(&xb[(size_t)(m0 + r) * 384 + k0 + c]);
      *reinterpret_cast<short8*>(&Bs[r][c]) =
          *reinterpret_cast<const short8*>(&wT[(size_t)(n0 + r) * 384 + k0 + c]);
    }
    __syncthreads();
#pragma unroll
    for (int kk = 0; kk < 2; ++kk) {
      short8 a[4], b[4];
#pragma unroll
      for (int f = 0; f < 4; ++f) {
        a[f] = *reinterpret_cast<const short8*>(&As[wm * 64 + f * 16 + lr][kk * 32 + lg * 8]);
        b[f] = *reinterpret_cast<const short8*>(&Bs[wn * 64 + f * 16 + lr][kk * 32 + lg * 8]);
      }
#pragma unroll
      for (int mf = 0; mf < 4; ++mf)
#pragma unroll
        for (int nf = 0; nf < 4; ++nf)
          acc[mf][nf] = MFMA16(a[mf], b[nf], acc[mf][nf]);
    }
  }

#pragma unroll
  for (int nf = 0; nf < 4; ++nf) {
    const int e = n0 + wn * 64 + nf * 16 + lr;         // 0..1151
    const float bv = bias[e];
    const int which = e / 384;                          // 0=q 1=k 2=v
    const int d = e - which * 384;
    const int h = d >> 6, hi = d & 63;
#pragma unroll
    for (int mf = 0; mf < 4; ++mf) {
#pragma unroll
      for (int j = 0; j < 4; ++j) {
        const int mm = m0 + wm * 64 + mf * 16 + lg * 4 + j;
        const float val = acc[mf][nf][j] + bv;
        const int b = mm >> 10, n = mm & 1023;
        const size_t bh = (size_t)(b * 6 + h);
        if (which == 0) {
          qb[bh * 65536 + (size_t)n * 64 + hi] = f2bf(val * 0.125f);
        } else if (which == 1) {
          kb[bh * 65536 + (size_t)n * 64 + hi] = f2bf(val);
        } else {
          const int np = (n & ~31) | ((n & 15) << 1) | ((n >> 4) & 1);
          vt[bh * 65536 + (size_t)hi * 1024 + np] = f2bf(val);
        }
      }
    }
  }
}

// ---------------- flash attention (no-max, deferred-sum, pipelined PV) ----------------
// grid = 96 (b,h) x 8 q-tiles of 128; 4 waves/block, each wave owns 32 queries.
// PV runs one K-tile behind QK through a double-buffered per-wave P in LDS,
// so the LDS round-trip and exp chain are off the MFMA critical path.
// P is packed as dwords with MANUAL RNE rounding (f2bf pair) — v_cvt_pk_bf16_f32
// truncates, which biased P low vs the fp32 lsum denominator (round-3 failure).
__global__ __launch_bounds__(256, 3) void attn(
    const unsigned short* __restrict__ qb,
    const unsigned short* __restrict__ kb,
    const unsigned short* __restrict__ vt,
    unsigned short* __restrict__ ab) {
  __shared__ alignas(16) unsigned short P[4][2][32][40];
  const int wg = (blockIdx.x & 7) * 96 + (blockIdx.x >> 3);
  const int bh = wg >> 3, qt = wg & 7;
  const int lane = threadIdx.x & 63, wid = threadIdx.x >> 6;
  const int lr = lane & 15, lg = lane >> 4;
  const size_t base = (size_t)bh * 65536;
  const unsigned short* qp = qb + base;
  const unsigned short* kp = kb + base;
  const unsigned short* vp = vt + base;
  const int q0 = qt * 128 + wid * 32;

  short8 aq[2][2];
#pragma unroll
  for (int qf = 0; qf < 2; ++qf)
#pragma unroll
    for (int h = 0; h < 2; ++h)
      aq[qf][h] = *reinterpret_cast<const short8*>(
          &qp[(size_t)(q0 + qf * 16 + lr) * 64 + h * 32 + lg * 8]);

  float lsum[2][4] = {};
  float4_t o[2][4] = {};
  unsigned short* Pb0 = &P[wid][0][0][0];
  unsigned short* Pb1 = &P[wid][1][0][0];

  auto loadK = [&](short8 (&bk)[2][2], int kb0) {
#pragma unroll
    for (int nf = 0; nf < 2; ++nf)
#pragma unroll
      for (int h = 0; h < 2; ++h)
        bk[nf][h] = *reinterpret_cast<const short8*>(
            &kp[(size_t)(kb0 + nf * 16 + lr) * 64 + h * 32 + lg * 8]);
  };
  auto loadV = [&](short8 (&bv)[4], int kb0) {
#pragma unroll
    for (int f = 0; f < 4; ++f)
      bv[f] = *reinterpret_cast<const short8*>(
          &vp[(size_t)(f * 16 + lr) * 1024 + kb0 + lg * 8]);
  };
  auto qkExpWrite = [&](const short8 (&bk)[2][2], unsigned short* Pbuf) {
    float4_t s[2][2] = {};
#pragma unroll
    for (int qf = 0; qf < 2; ++qf)
#pragma unroll
      for (int nf = 0; nf < 2; ++nf) {
        s[qf][nf] = MFMA16(aq[qf][0], bk[nf][0], s[qf][nf]);
        s[qf][nf] = MFMA16(aq[qf][1], bk[nf][1], s[qf][nf]);
      }
#pragma unroll
    for (int qf = 0; qf < 2; ++qf)
#pragma unroll
      for (int j = 0; j < 4; ++j) {
        const float p0 = __expf(s[qf][0][j]);   // scale pre-folded into Q
        const float p1 = __expf(s[qf][1][j]);
        lsum[qf][j] += p0 + p1;
        const unsigned int pk =
            (unsigned int)f2bf(p0) | ((unsigned int)f2bf(p1) << 16);
        *reinterpret_cast<unsigned int*>(
            &Pbuf[(qf * 16 + lg * 4 + j) * 40 + 2 * lr]) = pk;
      }
  };
  auto readPA = [&](short8 (&pa)[2], const unsigned short* Pbuf) {
    pa[0] = *reinterpret_cast<const short8*>(&Pbuf[(size_t)lr * 40 + lg * 8]);
    pa[1] = *reinterpret_cast<const short8*>(&Pbuf[(size_t)(16 + lr) * 40 + lg * 8]);
  };
  auto pv = [&](const short8 (&pa)[2], const short8 (&bv)[4]) {
#pragma unroll
    for (int f = 0; f < 4; ++f)
#pragma unroll
      for (int qf = 0; qf < 2; ++qf)
        o[qf][f] = MFMA16(pa[qf], bv[f], o[qf][f]);
  };

  short8 bkA[2][2], bkB[2][2], bvA[4], bvB[4], paA[2], paB[2];

  // prologue: tile 0
  loadK(bkA, 0);
  loadV(bvA, 0);
  qkExpWrite(bkA, Pb0);        // tile 0 -> buf0
  loadK(bkB, 32);              // K(1)

  for (int it = 0; it < 15; ++it) {
    const int kt1 = 2 * it + 1, kt2 = 2 * it + 2;
    // ---- tile kt1 (odd) ----
    readPA(paA, Pb0);          // P(kt1-1)
    loadV(bvB, kt1 * 32);      // V(kt1), used next half
    loadK(bkA, kt2 * 32);      // K(kt2), used next half
    qkExpWrite(bkB, Pb1);      // tile kt1 -> buf1
    pv(paA, bvA);              // PV(kt1-1)
    // ---- tile kt2 (even) ----
    readPA(paB, Pb1);          // P(kt1)
    loadV(bvA, kt2 * 32);      // V(kt2)
    loadK(bkB, (kt2 + 1) * 32);// K(kt2+1)
    qkExpWrite(bkA, Pb0);      // tile kt2 -> buf0
    pv(paB, bvB);              // PV(kt1)
  }
  // ---- tile 31 ----
  readPA(paA, Pb0);            // P(30)
  loadV(bvB, 31 * 32);
  qkExpWrite(bkB, Pb1);        // tile 31 -> buf1
  pv(paA, bvA);                // PV(30)
  readPA(paB, Pb1);
  pv(paB, bvB);                // PV(31)

  // one cross-lane reduction at the end (keys live in the lr dimension)
  float inv[2][4];
#pragma unroll
  for (int qf = 0; qf < 2; ++qf)
#pragma unroll
    for (int j = 0; j < 4; ++j) {
      float t = lsum[qf][j];
      t += __shfl_xor(t, 1);
      t += __shfl_xor(t, 2);
      t += __shfl_xor(t, 4);
      t += __shfl_xor(t, 8);
      inv[qf][j] = 1.f / t;
    }

  const int b = bh / 6, h = bh - b * 6;
#pragma unroll
  for (int qf = 0; qf < 2; ++qf)
#pragma unroll
    for (int f = 0; f < 4; ++f)
#pragma unroll
      for (int j = 0; j < 4; ++j) {
        const int q = q0 + qf * 16 + lg * 4 + j;
        ab[(size_t)(b * 1024 + q) * 384 + h * 64 + f * 16 + lr] =
            f2bf(o[qf][f][j] * inv[qf][j]);
      }
}

// ---------------- proj GEMM: (16384x384) @ (384x384) + bias -> fp32 ----------------
__global__ __launch_bounds__(256) void gemm_proj(
    const unsigned short* __restrict__ ab,
    const unsigned short* __restrict__ wT,
    const float* __restrict__ bias,
    float* __restrict__ out) {
  __shared__ alignas(16) unsigned short As[128][72];
  __shared__ alignas(16) unsigned short Bs[128][72];
  const int bm = blockIdx.x / 3, bn = blockIdx.x % 3;
  const int m0 = bm * 128, n0 = bn * 128;
  const int lane = threadIdx.x & 63, wid = threadIdx.x >> 6;
  const int lr = lane & 15, lg = lane >> 4;
  const int wm = wid >> 1, wn = wid & 1;
  float4_t acc[4][4] = {};

  for (int k0 = 0; k0 < 384; k0 += 64) {
    __syncthreads();
#pragma unroll
    for (int i = 0; i < 4; ++i) {
      int idx = threadIdx.x + i * 256;
      int r = idx >> 3, c = (idx & 7) * 8;
      *reinterpret_cast<short8*>(&As[r][c]) =
          *reinterpret_cast<const short8*>(&ab[(size_t)(m0 + r) * 384 + k0 + c]);
      *reinterpret_cast<short8*>(&Bs[r][c]) =
          *reinterpret_cast<const short8*>(&wT[(size_t)(n0 + r) * 384 + k0 + c]);
    }
    __syncthreads();
#pragma unroll
    for (int kk = 0; kk < 2; ++kk) {
      short8 a[4], b[4];
#pragma unroll
      for (int f = 0; f < 4; ++f) {
        a[f] = *reinterpret_cast<const short8*>(&As[wm * 64 + f * 16 + lr][kk * 32 + lg * 8]);
        b[f] = *reinterpret_cast<const short8*>(&Bs[wn * 64 + f * 16 + lr][kk * 32 + lg * 8]);
      }
#pragma unroll
      for (int mf = 0; mf < 4; ++mf)
#pragma unroll
        for (int nf = 0; nf < 4; ++nf)
          acc[mf][nf] = MFMA16(a[mf], b[nf], acc[mf][nf]);
    }
  }

#pragma unroll
  for (int nf = 0; nf < 4; ++nf) {
    const int e = n0 + wn * 64 + nf * 16 + lr;  // < 384
    const float bv = bias[e];
#pragma unroll
    for (int mf = 0; mf < 4; ++mf) {
#pragma unroll
      for (int j = 0; j < 4; ++j) {
        const int mm = m0 + wm * 64 + mf * 16 + lg * 4 + j;
        out[(size_t)mm * 384 + e] = acc[mf][nf][j] + bv;
      }
    }
  }
}

extern "C" void kernel_launch(void* const* d_in, const int* in_sizes, int n_in,
                              void* d_out, int out_size, void* d_ws, size_t ws_size,
                              hipStream_t stream) {
  const float* x      = (const float*)d_in[0];
  const float* w_qkv  = (const float*)d_in[1];
  const float* b_qkv  = (const float*)d_in[2];
  const float* w_proj = (const float*)d_in[3];
  const float* b_proj = (const float*)d_in[4];
  float* out = (float*)d_out;

  char* ws = (char*)d_ws;
  unsigned short* xb     = (unsigned short*)(ws);               // 12,582,912 B
  unsigned short* wqkvT  = (unsigned short*)(ws + 12582912);    //    884,736 B
  unsigned short* wprojT = (unsigned short*)(ws + 13467648);    //    294,912 B
  unsigned short* qb     = (unsigned short*)(ws + 13762560);    // 12,582,912 B
  unsigned short* kb     = (unsigned short*)(ws + 26345472);    // 12,582,912 B
  unsigned short* vt     = (unsigned short*)(ws + 38928384);    // 12,582,912 B
  unsigned short* ab     = xb;  // xb is dead after gemm_qkv; reuse for attn out

  cvt_f32_bf16<<<6144, 256, 0, stream>>>(x, xb, 16384 * 384 / 4);
  cvt_transpose<<<1728, 256, 0, stream>>>(w_qkv, wqkvT, 384, 1152);
  cvt_transpose<<<576, 256, 0, stream>>>(w_proj, wprojT, 384, 384);
  gemm_qkv<<<1152, 256, 0, stream>>>(xb, wqkvT, b_qkv, qb, kb, vt);
  attn<<<768, 256, 0, stream>>>(qb, kb, vt, ab);
  gemm_proj<<<384, 256, 0, stream>>>(ab, wprojT, b_proj, out);
}

// Round 5
// 170.930 us; speedup vs baseline: 1.0068x; 1.0068x over previous
//
#include <hip/hip_runtime.h>

typedef __attribute__((ext_vector_type(8))) short short8;
typedef __attribute__((ext_vector_type(4))) float float4_t;
typedef __attribute__((ext_vector_type(4))) unsigned int uint4_t;

#define MFMA16(A, B, C) __builtin_amdgcn_mfma_f32_16x16x32_bf16(A, B, C, 0, 0, 0)

__device__ __forceinline__ unsigned short f2bf(float f) {
  unsigned int u = __builtin_bit_cast(unsigned int, f);
  u += 0x7FFFu + ((u >> 16) & 1u);   // RNE
  return (unsigned short)(u >> 16);
}

// ---------------- conversion kernels ----------------
__global__ void cvt_f32_bf16(const float* __restrict__ in,
                             unsigned short* __restrict__ out, int n4) {
  int i = blockIdx.x * blockDim.x + threadIdx.x;
  if (i >= n4) return;
  float4 v = reinterpret_cast<const float4*>(in)[i];
  ushort4 r;
  r.x = f2bf(v.x); r.y = f2bf(v.y); r.z = f2bf(v.z); r.w = f2bf(v.w);
  reinterpret_cast<ushort4*>(out)[i] = r;
}

// w: D x E row-major -> wT: E x D row-major (bf16)
__global__ void cvt_transpose(const float* __restrict__ w,
                              unsigned short* __restrict__ wT, int D, int E) {
  int idx = blockIdx.x * blockDim.x + threadIdx.x;
  if (idx >= D * E) return;
  int e = idx / D, d = idx - e * D;
  wT[idx] = f2bf(w[d * E + e]);
}

// ---------------- QKV GEMM: (16384x384) @ (384x1152) + bias ----------------
// Scatter epilogue: q (pre-scaled by 0.125, exact in bf16) -> (B,H,N,hd),
// k -> (B,H,N,hd), v -> (B,H,hd,N) with key index PERMUTED within each
// 32-block: np = ((n&12)<<1)|((n&16)>>2)|(n&3).  This permutation makes the
// swapped-QK^T score fragment (key = kf*16+lg*4+j) line up with the PV
// A-fragment k-slots (key-slot = lg*8+2m+t) WITHOUT any cross-lane transpose.
__global__ __launch_bounds__(256) void gemm_qkv(
    const unsigned short* __restrict__ xb,
    const unsigned short* __restrict__ wT,
    const float* __restrict__ bias,
    unsigned short* __restrict__ qb,
    unsigned short* __restrict__ kb,
    unsigned short* __restrict__ vt) {
  __shared__ alignas(16) unsigned short As[128][72];
  __shared__ alignas(16) unsigned short Bs[128][72];
  const int bm = blockIdx.x / 9, bn = blockIdx.x % 9;
  const int m0 = bm * 128, n0 = bn * 128;
  const int lane = threadIdx.x & 63, wid = threadIdx.x >> 6;
  const int lr = lane & 15, lg = lane >> 4;
  const int wm = wid >> 1, wn = wid & 1;
  float4_t acc[4][4] = {};

  for (int k0 = 0; k0 < 384; k0 += 64) {
    __syncthreads();
#pragma unroll
    for (int i = 0; i < 4; ++i) {
      int idx = threadIdx.x + i * 256;
      int r = idx >> 3, c = (idx & 7) * 8;
      *reinterpret_cast<short8*>(&As[r][c]) =
          *reinterpret_cast<const short8*>(&xb[(size_t)(m0 + r) * 384 + k0 + c]);
      *reinterpret_cast<short8*>(&Bs[r][c]) =
          *reinterpret_cast<const short8*>(&wT[(size_t)(n0 + r) * 384 + k0 + c]);
    }
    __syncthreads();
#pragma unroll
    for (int kk = 0; kk < 2; ++kk) {
      short8 a[4], b[4];
#pragma unroll
      for (int f = 0; f < 4; ++f) {
        a[f] = *reinterpret_cast<const short8*>(&As[wm * 64 + f * 16 + lr][kk * 32 + lg * 8]);
        b[f] = *reinterpret_cast<const short8*>(&Bs[wn * 64 + f * 16 + lr][kk * 32 + lg * 8]);
      }
#pragma unroll
      for (int mf = 0; mf < 4; ++mf)
#pragma unroll
        for (int nf = 0; nf < 4; ++nf)
          acc[mf][nf] = MFMA16(a[mf], b[nf], acc[mf][nf]);
    }
  }

#pragma unroll
  for (int nf = 0; nf < 4; ++nf) {
    const int e = n0 + wn * 64 + nf * 16 + lr;         // 0..1151
    const float bv = bias[e];
    const int which = e / 384;                          // 0=q 1=k 2=v
    const int d = e - which * 384;
    const int h = d >> 6, hi = d & 63;
#pragma unroll
    for (int mf = 0; mf < 4; ++mf) {
#pragma unroll
      for (int j = 0; j < 4; ++j) {
        const int mm = m0 + wm * 64 + mf * 16 + lg * 4 + j;
        const float val = acc[mf][nf][j] + bv;
        const int b = mm >> 10, n = mm & 1023;
        const size_t bh = (size_t)(b * 6 + h);
        if (which == 0) {
          qb[bh * 65536 + (size_t)n * 64 + hi] = f2bf(val * 0.125f);
        } else if (which == 1) {
          kb[bh * 65536 + (size_t)n * 64 + hi] = f2bf(val);
        } else {
          const int np = (n & ~31) | ((n & 12) << 1) | ((n & 16) >> 2) | (n & 3);
          vt[bh * 65536 + (size_t)hi * 1024 + np] = f2bf(val);
        }
      }
    }
  }
}

// ---------------- flash attention (swapped QK^T, in-register P) ----------------
// grid = 96 (b,h) x 8 q-tiles of 128; 4 waves/block, each wave owns 32 queries.
// QK^T is computed as mfma(K, Q) so the score fragment has query = lr (lane-
// local row of P).  With V's key order pre-permuted at the QKV scatter, the
// PV A-fragment is assembled from the lane's OWN packed bf16 dwords — no LDS,
// no shuffles, no cross-lane traffic anywhere in the K sweep.
__global__ __launch_bounds__(256, 3) void attn(
    const unsigned short* __restrict__ qb,
    const unsigned short* __restrict__ kb,
    const unsigned short* __restrict__ vt,
    unsigned short* __restrict__ ab) {
  const int wg = (blockIdx.x & 7) * 96 + (blockIdx.x >> 3);
  const int bh = wg >> 3, qt = wg & 7;
  const int lane = threadIdx.x & 63, wid = threadIdx.x >> 6;
  const int lr = lane & 15, lg = lane >> 4;
  const size_t base = (size_t)bh * 65536;
  const unsigned short* qp = qb + base;
  const unsigned short* kp = kb + base;
  const unsigned short* vp = vt + base;
  const int q0 = qt * 128 + wid * 32;

  short8 aq[2][2];   // Q as B-operand: col=lr=query, k=d
#pragma unroll
  for (int qf = 0; qf < 2; ++qf)
#pragma unroll
    for (int h = 0; h < 2; ++h)
      aq[qf][h] = *reinterpret_cast<const short8*>(
          &qp[(size_t)(q0 + qf * 16 + lr) * 64 + h * 32 + lg * 8]);

  float lsum[2] = {0.f, 0.f};   // per-lane partial denom for query qf*16+lr
  float4_t o[2][4] = {};

  auto loadK = [&](short8 (&bk)[2][2], int kb0) {
#pragma unroll
    for (int kf = 0; kf < 2; ++kf)
#pragma unroll
      for (int h = 0; h < 2; ++h)
        bk[kf][h] = *reinterpret_cast<const short8*>(
            &kp[(size_t)(kb0 + kf * 16 + lr) * 64 + h * 32 + lg * 8]);
  };
  auto loadV = [&](short8 (&bv)[4], int kb0) {
#pragma unroll
    for (int f = 0; f < 4; ++f)
      bv[f] = *reinterpret_cast<const short8*>(
          &vp[(size_t)(f * 16 + lr) * 1024 + kb0 + lg * 8]);
  };
  auto compute = [&](const short8 (&bk)[2][2], const short8 (&bv)[4]) {
    float4_t s[2][2] = {};   // [kf][qf]; D: col=lr=query, row=lg*4+j=key
#pragma unroll
    for (int kf = 0; kf < 2; ++kf)
#pragma unroll
      for (int qf = 0; qf < 2; ++qf) {
        s[kf][qf] = MFMA16(bk[kf][0], aq[qf][0], s[kf][qf]);
        s[kf][qf] = MFMA16(bk[kf][1], aq[qf][1], s[kf][qf]);
      }
    unsigned int dw[2][2][2];  // [kf][qf][lo/hi pair]
#pragma unroll
    for (int kf = 0; kf < 2; ++kf)
#pragma unroll
      for (int qf = 0; qf < 2; ++qf) {
        const float p0 = __expf(s[kf][qf][0]);   // scale pre-folded into Q
        const float p1 = __expf(s[kf][qf][1]);
        const float p2 = __expf(s[kf][qf][2]);
        const float p3 = __expf(s[kf][qf][3]);
        lsum[qf] += (p0 + p1) + (p2 + p3);
        dw[kf][qf][0] = (unsigned int)f2bf(p0) | ((unsigned int)f2bf(p1) << 16);
        dw[kf][qf][1] = (unsigned int)f2bf(p2) | ((unsigned int)f2bf(p3) << 16);
      }
#pragma unroll
    for (int qf = 0; qf < 2; ++qf) {
      uint4_t pw;
      pw[0] = dw[0][qf][0];  // key-slots lg*8+0,1  (keys lg*4+0,1)
      pw[1] = dw[0][qf][1];  // key-slots lg*8+2,3  (keys lg*4+2,3)
      pw[2] = dw[1][qf][0];  // key-slots lg*8+4,5  (keys 16+lg*4+0,1)
      pw[3] = dw[1][qf][1];  // key-slots lg*8+6,7  (keys 16+lg*4+2,3)
      const short8 pa = __builtin_bit_cast(short8, pw);
#pragma unroll
      for (int f = 0; f < 4; ++f)
        o[qf][f] = MFMA16(pa, bv[f], o[qf][f]);
    }
  };

  short8 bkA[2][2], bkB[2][2], bvA[4], bvB[4];

  loadK(bkA, 0);
  loadV(bvA, 0);
  for (int it = 0; it < 15; ++it) {
    const int t = 2 * it;
    loadK(bkB, (t + 1) * 32);
    loadV(bvB, (t + 1) * 32);
    compute(bkA, bvA);
    loadK(bkA, (t + 2) * 32);
    loadV(bvA, (t + 2) * 32);
    compute(bkB, bvB);
  }
  loadK(bkB, 31 * 32);
  loadV(bvB, 31 * 32);
  compute(bkA, bvA);
  compute(bkB, bvB);

  // denom: reduce per-lane partials over lg (lanes lr+16*lg hold query lr)
  float inv[2];
#pragma unroll
  for (int qf = 0; qf < 2; ++qf) {
    float t = lsum[qf];
    t += __shfl_xor(t, 16);
    t += __shfl_xor(t, 32);
    inv[qf] = 1.f / t;
  }

  const int b = bh / 6, h = bh - b * 6;
#pragma unroll
  for (int qf = 0; qf < 2; ++qf) {
    float invj[4];
#pragma unroll
    for (int j = 0; j < 4; ++j)
      invj[j] = __shfl(inv[qf], lg * 4 + j);   // denom of query lg*4+j
#pragma unroll
    for (int f = 0; f < 4; ++f)
#pragma unroll
      for (int j = 0; j < 4; ++j) {
        const int q = q0 + qf * 16 + lg * 4 + j;
        ab[(size_t)(b * 1024 + q) * 384 + h * 64 + f * 16 + lr] =
            f2bf(o[qf][f][j] * invj[j]);
      }
  }
}

// ---------------- proj GEMM: (16384x384) @ (384x384) + bias -> fp32 ----------------
__global__ __launch_bounds__(256) void gemm_proj(
    const unsigned short* __restrict__ ab,
    const unsigned short* __restrict__ wT,
    const float* __restrict__ bias,
    float* __restrict__ out) {
  __shared__ alignas(16) unsigned short As[128][72];
  __shared__ alignas(16) unsigned short Bs[128][72];
  const int bm = blockIdx.x / 3, bn = blockIdx.x % 3;
  const int m0 = bm * 128, n0 = bn * 128;
  const int lane = threadIdx.x & 63, wid = threadIdx.x >> 6;
  const int lr = lane & 15, lg = lane >> 4;
  const int wm = wid >> 1, wn = wid & 1;
  float4_t acc[4][4] = {};

  for (int k0 = 0; k0 < 384; k0 += 64) {
    __syncthreads();
#pragma unroll
    for (int i = 0; i < 4; ++i) {
      int idx = threadIdx.x + i * 256;
      int r = idx >> 3, c = (idx & 7) * 8;
      *reinterpret_cast<short8*>(&As[r][c]) =
          *reinterpret_cast<const short8*>(&ab[(size_t)(m0 + r) * 384 + k0 + c]);
      *reinterpret_cast<short8*>(&Bs[r][c]) =
          *reinterpret_cast<const short8*>(&wT[(size_t)(n0 + r) * 384 + k0 + c]);
    }
    __syncthreads();
#pragma unroll
    for (int kk = 0; kk < 2; ++kk) {
      short8 a[4], b[4];
#pragma unroll
      for (int f = 0; f < 4; ++f) {
        a[f] = *reinterpret_cast<const short8*>(&As[wm * 64 + f * 16 + lr][kk * 32 + lg * 8]);
        b[f] = *reinterpret_cast<const short8*>(&Bs[wn * 64 + f * 16 + lr][kk * 32 + lg * 8]);
      }
#pragma unroll
      for (int mf = 0; mf < 4; ++mf)
#pragma unroll
        for (int nf = 0; nf < 4; ++nf)
          acc[mf][nf] = MFMA16(a[mf], b[nf], acc[mf][nf]);
    }
  }

#pragma unroll
  for (int nf = 0; nf < 4; ++nf) {
    const int e = n0 + wn * 64 + nf * 16 + lr;  // < 384
    const float bv = bias[e];
#pragma unroll
    for (int mf = 0; mf < 4; ++mf) {
#pragma unroll
      for (int j = 0; j < 4; ++j) {
        const int mm = m0 + wm * 64 + mf * 16 + lg * 4 + j;
        out[(size_t)mm * 384 + e] = acc[mf][nf][j] + bv;
      }
    }
  }
}

extern "C" void kernel_launch(void* const* d_in, const int* in_sizes, int n_in,
                              void* d_out, int out_size, void* d_ws, size_t ws_size,
                              hipStream_t stream) {
  const float* x      = (const float*)d_in[0];
  const float* w_qkv  = (const float*)d_in[1];
  const float* b_qkv  = (const float*)d_in[2];
  const float* w_proj = (const float*)d_in[3];
  const float* b_proj = (const float*)d_in[4];
  float* out = (float*)d_out;

  char* ws = (char*)d_ws;
  unsigned short* xb     = (unsigned short*)(ws);               // 12,582,912 B
  unsigned short* wqkvT  = (unsigned short*)(ws + 12582912);    //    884,736 B
  unsigned short* wprojT = (unsigned short*)(ws + 13467648);    //    294,912 B
  unsigned short* qb     = (unsigned short*)(ws + 13762560);    // 12,582,912 B
  unsigned short* kb     = (unsigned short*)(ws + 26345472);    // 12,582,912 B
  unsigned short* vt     = (unsigned short*)(ws + 38928384);    // 12,582,912 B
  unsigned short* ab     = xb;  // xb is dead after gemm_qkv; reuse for attn out

  cvt_f32_bf16<<<6144, 256, 0, stream>>>(x, xb, 16384 * 384 / 4);
  cvt_transpose<<<1728, 256, 0, stream>>>(w_qkv, wqkvT, 384, 1152);
  cvt_transpose<<<576, 256, 0, stream>>>(w_proj, wprojT, 384, 384);
  gemm_qkv<<<1152, 256, 0, stream>>>(xb, wqkvT, b_qkv, qb, kb, vt);
  attn<<<768, 256, 0, stream>>>(qb, kb, vt, ab);
  gemm_proj<<<384, 256, 0, stream>>>(ab, wprojT, b_proj, out);
}

// Round 6
// 123.620 us; speedup vs baseline: 1.3921x; 1.3827x over previous
//
#include <hip/hip_runtime.h>

typedef __attribute__((ext_vector_type(8))) short short8;
typedef __attribute__((ext_vector_type(4))) float float4_t;
typedef __attribute__((ext_vector_type(4))) unsigned int uint4_t;

#define MFMA16(A, B, C) __builtin_amdgcn_mfma_f32_16x16x32_bf16(A, B, C, 0, 0, 0)

__device__ __forceinline__ unsigned short f2bf(float f) {
  unsigned int u = __builtin_bit_cast(unsigned int, f);
  u += 0x7FFFu + ((u >> 16) & 1u);   // RNE
  return (unsigned short)(u >> 16);
}

__device__ __forceinline__ void gload16(const unsigned short* g, unsigned short* l) {
  __builtin_amdgcn_global_load_lds(
      (const __attribute__((address_space(1))) unsigned int*)(g),
      (__attribute__((address_space(3))) unsigned int*)(l), 16, 0, 0);
}

// ---------------- conversion kernels ----------------
__global__ void cvt_f32_bf16(const float* __restrict__ in,
                             unsigned short* __restrict__ out, int n4) {
  int i = blockIdx.x * blockDim.x + threadIdx.x;
  if (i >= n4) return;
  float4 v = reinterpret_cast<const float4*>(in)[i];
  ushort4 r;
  r.x = f2bf(v.x); r.y = f2bf(v.y); r.z = f2bf(v.z); r.w = f2bf(v.w);
  reinterpret_cast<ushort4*>(out)[i] = r;
}

// w: D x E row-major -> wT: E x D row-major (bf16)
__global__ void cvt_transpose(const float* __restrict__ w,
                              unsigned short* __restrict__ wT, int D, int E) {
  int idx = blockIdx.x * blockDim.x + threadIdx.x;
  if (idx >= D * E) return;
  int e = idx / D, d = idx - e * D;
  wT[idx] = f2bf(w[d * E + e]);
}

// ---------------- QKV GEMM: (16384x384) @ (384x1152) + bias ----------------
// Scatter epilogue: q (pre-scaled by 0.125, exact in bf16) -> (B,H,N,hd),
// k -> (B,H,N,hd), v -> (B,H,hd,N) with key index PERMUTED within each
// 32-block: np = ((n&12)<<1)|((n&16)>>2)|(n&3), matching the swapped-QK^T
// score-fragment -> PV A-fragment key-slot order (no cross-lane transpose).
__global__ __launch_bounds__(256) void gemm_qkv(
    const unsigned short* __restrict__ xb,
    const unsigned short* __restrict__ wT,
    const float* __restrict__ bias,
    unsigned short* __restrict__ qb,
    unsigned short* __restrict__ kb,
    unsigned short* __restrict__ vt) {
  __shared__ alignas(16) unsigned short As[128][72];
  __shared__ alignas(16) unsigned short Bs[128][72];
  const int bm = blockIdx.x / 9, bn = blockIdx.x % 9;
  const int m0 = bm * 128, n0 = bn * 128;
  const int lane = threadIdx.x & 63, wid = threadIdx.x >> 6;
  const int lr = lane & 15, lg = lane >> 4;
  const int wm = wid >> 1, wn = wid & 1;
  float4_t acc[4][4] = {};

  for (int k0 = 0; k0 < 384; k0 += 64) {
    __syncthreads();
#pragma unroll
    for (int i = 0; i < 4; ++i) {
      int idx = threadIdx.x + i * 256;
      int r = idx >> 3, c = (idx & 7) * 8;
      *reinterpret_cast<short8*>(&As[r][c]) =
          *reinterpret_cast<const short8*>(&xb[(size_t)(m0 + r) * 384 + k0 + c]);
      *reinterpret_cast<short8*>(&Bs[r][c]) =
          *reinterpret_cast<const short8*>(&wT[(size_t)(n0 + r) * 384 + k0 + c]);
    }
    __syncthreads();
#pragma unroll
    for (int kk = 0; kk < 2; ++kk) {
      short8 a[4], b[4];
#pragma unroll
      for (int f = 0; f < 4; ++f) {
        a[f] = *reinterpret_cast<const short8*>(&As[wm * 64 + f * 16 + lr][kk * 32 + lg * 8]);
        b[f] = *reinterpret_cast<const short8*>(&Bs[wn * 64 + f * 16 + lr][kk * 32 + lg * 8]);
      }
#pragma unroll
      for (int mf = 0; mf < 4; ++mf)
#pragma unroll
        for (int nf = 0; nf < 4; ++nf)
          acc[mf][nf] = MFMA16(a[mf], b[nf], acc[mf][nf]);
    }
  }

#pragma unroll
  for (int nf = 0; nf < 4; ++nf) {
    const int e = n0 + wn * 64 + nf * 16 + lr;         // 0..1151
    const float bv = bias[e];
    const int which = e / 384;                          // 0=q 1=k 2=v
    const int d = e - which * 384;
    const int h = d >> 6, hi = d & 63;
#pragma unroll
    for (int mf = 0; mf < 4; ++mf) {
#pragma unroll
      for (int j = 0; j < 4; ++j) {
        const int mm = m0 + wm * 64 + mf * 16 + lg * 4 + j;
        const float val = acc[mf][nf][j] + bv;
        const int b = mm >> 10, n = mm & 1023;
        const size_t bh = (size_t)(b * 6 + h);
        if (which == 0) {
          qb[bh * 65536 + (size_t)n * 64 + hi] = f2bf(val * 0.125f);
        } else if (which == 1) {
          kb[bh * 65536 + (size_t)n * 64 + hi] = f2bf(val);
        } else {
          const int np = (n & ~31) | ((n & 12) << 1) | ((n & 16) >> 2) | (n & 3);
          vt[bh * 65536 + (size_t)hi * 1024 + np] = f2bf(val);
        }
      }
    }
  }
}

// ---------------- flash attention v3: LDS-staged K/V, 6 blocks/CU ----------------
// grid = 96 (b,h) x 16 q-tiles of 64; 4 waves/block, each wave owns 16 queries.
// Per k-tile the block stages K (4KB) + V (4KB) ONCE into double-buffered LDS
// via global_load_lds (2-phase counted-prefetch: stage(t+1) issued before
// compute(t); the vmcnt(0) in the single per-tile barrier drains loads issued
// a full compute-phase earlier). LDS reads are XOR-swizzled; inverse swizzle
// is pre-applied to the global SOURCE address (linear-dest rule, G21).
__global__ __launch_bounds__(256, 6) void attn(
    const unsigned short* __restrict__ qb,
    const unsigned short* __restrict__ kb,
    const unsigned short* __restrict__ vt,
    unsigned short* __restrict__ ab) {
  __shared__ alignas(16) char smem[16384];  // [2][4KB K] then [2][4KB V]
  const int tid = threadIdx.x;
  const int wg = (blockIdx.x & 7) * 192 + (blockIdx.x >> 3);  // XCD swizzle
  const int bh = wg >> 4, qt = wg & 15;
  const int lane = tid & 63, wid = tid >> 6;
  const int lr = lane & 15, lg = lane >> 4;
  const size_t base = (size_t)bh * 65536;
  const unsigned short* qp = qb + base;
  const unsigned short* kp = kb + base;
  const unsigned short* vp = vt + base;
  const int q0 = qt * 64 + wid * 16;

  short8 aq0 = *reinterpret_cast<const short8*>(&qp[(size_t)(q0 + lr) * 64 + lg * 8]);
  short8 aq1 = *reinterpret_cast<const short8*>(&qp[(size_t)(q0 + lr) * 64 + 32 + lg * 8]);

  // stage-source indices (pre-swizzled so linear LDS dest + swizzled read match)
  const int rK = tid >> 3;
  const int cK = (((tid & 7) * 16) ^ ((rK & 7) << 4)) >> 1;   // element col in K row
  const int rV = tid >> 2;
  const int cV = (((tid & 3) * 16) ^ ((rV & 3) << 4)) >> 1;   // element col in V tile row
  const unsigned short* ksrc = kp + rK * 64 + cK;              // + kt*2048
  const unsigned short* vsrc = vp + rV * 1024 + cV;            // + kt*32
  unsigned short* kdst0 = (unsigned short*)(smem + wid * 1024);
  unsigned short* vdst0 = (unsigned short*)(smem + 8192 + wid * 1024);

  // read-side swizzled byte offsets
  const int kxor = (lr & 7) << 4;
  const int vxor = (lr & 3) << 4;

  float lsum = 0.f;
  float4_t o[4] = {};

  // prologue: stage tile 0 into buf 0
  gload16(ksrc, kdst0);
  gload16(vsrc, vdst0);
  __syncthreads();

  for (int kt = 0; kt < 32; ++kt) {
    const int cur = kt & 1;
    if (kt < 31) {  // stage tile kt+1 into buf cur^1 (issued before compute)
      const int nb = (cur ^ 1) * 4096;
      gload16(ksrc + (kt + 1) * 2048, (unsigned short*)((char*)kdst0 + nb));
      gload16(vsrc + (kt + 1) * 32, (unsigned short*)((char*)vdst0 + nb));
    }
    const char* kbase = smem + cur * 4096;
    const char* vbase = smem + 8192 + cur * 4096;

    short8 bk[2][2], bv[4];
#pragma unroll
    for (int kf = 0; kf < 2; ++kf)
#pragma unroll
      for (int h = 0; h < 2; ++h)
        bk[kf][h] = *reinterpret_cast<const short8*>(
            kbase + (kf * 16 + lr) * 128 + ((h * 64 + lg * 16) ^ kxor));
#pragma unroll
    for (int f = 0; f < 4; ++f)
      bv[f] = *reinterpret_cast<const short8*>(
          vbase + (f * 16 + lr) * 64 + ((lg * 16) ^ vxor));

    float4_t s[2] = {};
#pragma unroll
    for (int kf = 0; kf < 2; ++kf) {
      s[kf] = MFMA16(bk[kf][0], aq0, s[kf]);
      s[kf] = MFMA16(bk[kf][1], aq1, s[kf]);
    }
    unsigned int dw[4];
#pragma unroll
    for (int kf = 0; kf < 2; ++kf) {
      const float p0 = __expf(s[kf][0]);   // softmax scale pre-folded into Q
      const float p1 = __expf(s[kf][1]);
      const float p2 = __expf(s[kf][2]);
      const float p3 = __expf(s[kf][3]);
      lsum += (p0 + p1) + (p2 + p3);
      dw[kf * 2]     = (unsigned int)f2bf(p0) | ((unsigned int)f2bf(p1) << 16);
      dw[kf * 2 + 1] = (unsigned int)f2bf(p2) | ((unsigned int)f2bf(p3) << 16);
    }
    uint4_t pw;
    pw[0] = dw[0]; pw[1] = dw[1]; pw[2] = dw[2]; pw[3] = dw[3];
    const short8 pa = __builtin_bit_cast(short8, pw);
#pragma unroll
    for (int f = 0; f < 4; ++f)
      o[f] = MFMA16(pa, bv[f], o[f]);

    __syncthreads();  // includes vmcnt(0): drains the stage issued above
  }

  // denominator: per-lane partials (query = lr) summed over lg groups
  float t = lsum;
  t += __shfl_xor(t, 16);
  t += __shfl_xor(t, 32);
  const float inv = 1.f / t;

  const int b = bh / 6, h = bh - b * 6;
  float invj[4];
#pragma unroll
  for (int j = 0; j < 4; ++j)
    invj[j] = __shfl(inv, lg * 4 + j);   // denom of query lg*4+j
#pragma unroll
  for (int f = 0; f < 4; ++f)
#pragma unroll
    for (int j = 0; j < 4; ++j) {
      const int q = q0 + lg * 4 + j;
      ab[(size_t)(b * 1024 + q) * 384 + h * 64 + f * 16 + lr] =
          f2bf(o[f][j] * invj[j]);
    }
}

// ---------------- proj GEMM: (16384x384) @ (384x384) + bias -> fp32 ----------------
__global__ __launch_bounds__(256) void gemm_proj(
    const unsigned short* __restrict__ ab,
    const unsigned short* __restrict__ wT,
    const float* __restrict__ bias,
    float* __restrict__ out) {
  __shared__ alignas(16) unsigned short As[128][72];
  __shared__ alignas(16) unsigned short Bs[128][72];
  const int bm = blockIdx.x / 3, bn = blockIdx.x % 3;
  const int m0 = bm * 128, n0 = bn * 128;
  const int lane = threadIdx.x & 63, wid = threadIdx.x >> 6;
  const int lr = lane & 15, lg = lane >> 4;
  const int wm = wid >> 1, wn = wid & 1;
  float4_t acc[4][4] = {};

  for (int k0 = 0; k0 < 384; k0 += 64) {
    __syncthreads();
#pragma unroll
    for (int i = 0; i < 4; ++i) {
      int idx = threadIdx.x + i * 256;
      int r = idx >> 3, c = (idx & 7) * 8;
      *reinterpret_cast<short8*>(&As[r][c]) =
          *reinterpret_cast<const short8*>(&ab[(size_t)(m0 + r) * 384 + k0 + c]);
      *reinterpret_cast<short8*>(&Bs[r][c]) =
          *reinterpret_cast<const short8*>(&wT[(size_t)(n0 + r) * 384 + k0 + c]);
    }
    __syncthreads();
#pragma unroll
    for (int kk = 0; kk < 2; ++kk) {
      short8 a[4], b[4];
#pragma unroll
      for (int f = 0; f < 4; ++f) {
        a[f] = *reinterpret_cast<const short8*>(&As[wm * 64 + f * 16 + lr][kk * 32 + lg * 8]);
        b[f] = *reinterpret_cast<const short8*>(&Bs[wn * 64 + f * 16 + lr][kk * 32 + lg * 8]);
      }
#pragma unroll
      for (int mf = 0; mf < 4; ++mf)
#pragma unroll
        for (int nf = 0; nf < 4; ++nf)
          acc[mf][nf] = MFMA16(a[mf], b[nf], acc[mf][nf]);
    }
  }

#pragma unroll
  for (int nf = 0; nf < 4; ++nf) {
    const int e = n0 + wn * 64 + nf * 16 + lr;  // < 384
    const float bv = bias[e];
#pragma unroll
    for (int mf = 0; mf < 4; ++mf) {
#pragma unroll
      for (int j = 0; j < 4; ++j) {
        const int mm = m0 + wm * 64 + mf * 16 + lg * 4 + j;
        out[(size_t)mm * 384 + e] = acc[mf][nf][j] + bv;
      }
    }
  }
}

extern "C" void kernel_launch(void* const* d_in, const int* in_sizes, int n_in,
                              void* d_out, int out_size, void* d_ws, size_t ws_size,
                              hipStream_t stream) {
  const float* x      = (const float*)d_in[0];
  const float* w_qkv  = (const float*)d_in[1];
  const float* b_qkv  = (const float*)d_in[2];
  const float* w_proj = (const float*)d_in[3];
  const float* b_proj = (const float*)d_in[4];
  float* out = (float*)d_out;

  char* ws = (char*)d_ws;
  unsigned short* xb     = (unsigned short*)(ws);               // 12,582,912 B
  unsigned short* wqkvT  = (unsigned short*)(ws + 12582912);    //    884,736 B
  unsigned short* wprojT = (unsigned short*)(ws + 13467648);    //    294,912 B
  unsigned short* qb     = (unsigned short*)(ws + 13762560);    // 12,582,912 B
  unsigned short* kb     = (unsigned short*)(ws + 26345472);    // 12,582,912 B
  unsigned short* vt     = (unsigned short*)(ws + 38928384);    // 12,582,912 B
  unsigned short* ab     = xb;  // xb is dead after gemm_qkv; reuse for attn out

  cvt_f32_bf16<<<6144, 256, 0, stream>>>(x, xb, 16384 * 384 / 4);
  cvt_transpose<<<1728, 256, 0, stream>>>(w_qkv, wqkvT, 384, 1152);
  cvt_transpose<<<576, 256, 0, stream>>>(w_proj, wprojT, 384, 384);
  gemm_qkv<<<1152, 256, 0, stream>>>(xb, wqkvT, b_qkv, qb, kb, vt);
  attn<<<1536, 256, 0, stream>>>(qb, kb, vt, ab);
  gemm_proj<<<384, 256, 0, stream>>>(ab, wprojT, b_proj, out);
}

// Round 7
// 96.105 us; speedup vs baseline: 1.7907x; 1.2863x over previous
//
#include <hip/hip_runtime.h>

typedef __attribute__((ext_vector_type(8))) short short8;
typedef __attribute__((ext_vector_type(4))) float float4_t;
typedef __attribute__((ext_vector_type(4))) unsigned int uint4_t;

#define MFMA16(A, B, C) __builtin_amdgcn_mfma_f32_16x16x32_bf16(A, B, C, 0, 0, 0)

__device__ __forceinline__ unsigned short f2bf(float f) {
  unsigned int u = __builtin_bit_cast(unsigned int, f);
  u += 0x7FFFu + ((u >> 16) & 1u);   // RNE
  return (unsigned short)(u >> 16);
}

__device__ __forceinline__ void gload16(const unsigned short* g, unsigned short* l) {
  __builtin_amdgcn_global_load_lds(
      (const __attribute__((address_space(1))) unsigned int*)(g),
      (__attribute__((address_space(3))) unsigned int*)(l), 16, 0, 0);
}

// ---------------- prep: x->bf16 cvt + both weight transposes, one launch ----------------
// blocks [0,6144): x cvt (float4->ushort4). [6144,6576): w_qkv 32x32 tile
// transpose. [6576,6720): w_proj. Tiled transpose: coalesced reads AND writes.
__global__ __launch_bounds__(256) void prep(
    const float* __restrict__ x, const float* __restrict__ w_qkv,
    const float* __restrict__ w_proj, unsigned short* __restrict__ xb,
    unsigned short* __restrict__ wqkvT, unsigned short* __restrict__ wprojT) {
  __shared__ unsigned short tile[32][33];
  const int bid = blockIdx.x, tid = threadIdx.x;
  if (bid < 6144) {
    const int i = bid * 256 + tid;
    float4 v = reinterpret_cast<const float4*>(x)[i];
    ushort4 r;
    r.x = f2bf(v.x); r.y = f2bf(v.y); r.z = f2bf(v.z); r.w = f2bf(v.w);
    reinterpret_cast<ushort4*>(xb)[i] = r;
    return;
  }
  const float* w; unsigned short* wT; int E, t;
  if (bid < 6576) { t = bid - 6144; w = w_qkv; wT = wqkvT; E = 1152; }
  else            { t = bid - 6576; w = w_proj; wT = wprojT; E = 384; }
  const int tiles_e = E >> 5;
  const int td = t / tiles_e, te = t - td * tiles_e;
  const int r = tid >> 3, c4 = (tid & 7) * 4;
  float4 v = *reinterpret_cast<const float4*>(&w[(size_t)(td * 32 + r) * E + te * 32 + c4]);
  tile[r][c4 + 0] = f2bf(v.x);
  tile[r][c4 + 1] = f2bf(v.y);
  tile[r][c4 + 2] = f2bf(v.z);
  tile[r][c4 + 3] = f2bf(v.w);
  __syncthreads();
  ushort4 o;
  o.x = tile[c4 + 0][r]; o.y = tile[c4 + 1][r];
  o.z = tile[c4 + 2][r]; o.w = tile[c4 + 3][r];
  *reinterpret_cast<ushort4*>(&wT[(size_t)(te * 32 + r) * 384 + td * 32 + c4]) = o;
}

// ---------------- QKV GEMM v2: (16384x384)@(384x1152)+bias ----------------
// 128x128 tile, BK=64, global_load_lds staging into double-buffered XOR-
// swizzled LDS (swizzle pre-applied to the global SOURCE address), 2-phase
// prefetch (stage t+1 issued before compute t), one barrier per K-step.
// Scatter epilogue unchanged: q pre-scaled 0.125 -> (B,H,N,hd); k -> same;
// v -> (B,H,hd,N) with key-permutation np = (n&~31)|((n&12)<<1)|((n&16)>>2)|(n&3)
// (v stores vectorized: j=0..3 are np-contiguous -> one 8B store).
__global__ __launch_bounds__(256, 2) void gemm_qkv(
    const unsigned short* __restrict__ xb,
    const unsigned short* __restrict__ wT,
    const float* __restrict__ bias,
    unsigned short* __restrict__ qb,
    unsigned short* __restrict__ kb,
    unsigned short* __restrict__ vt) {
  __shared__ alignas(16) char smem[65536];  // A:2x16KB @0, B:2x16KB @32768
  const int tid = threadIdx.x;
  const int wg = (blockIdx.x & 7) * 144 + (blockIdx.x >> 3);  // XCD: 16 bm x 9 bn per XCD
  const int bm = wg / 9, bn = wg - bm * 9;
  const int m0 = bm * 128, n0 = bn * 128;
  const int lane = tid & 63, wid = tid >> 6;
  const int lr = lane & 15, lg = lane >> 4;
  const int wm = wid >> 1, wn = wid & 1;
  float4_t acc[4][4] = {};

  const unsigned short* asrc[4];
  const unsigned short* bsrc[4];
  int dstoff[4];
#pragma unroll
  for (int i = 0; i < 4; ++i) {
    const int idx = tid + i * 256;
    const int r = idx >> 3, c8 = idx & 7;
    const int cc = (c8 ^ (r & 7)) * 8;   // inverse-swizzled source column
    asrc[i] = xb + (size_t)(m0 + r) * 384 + cc;
    bsrc[i] = wT + (size_t)(n0 + r) * 384 + cc;
    dstoff[i] = idx * 16;
  }
  const int rxor = (lr & 7) << 4;

  // prologue: stage K-step 0 into buf 0
#pragma unroll
  for (int i = 0; i < 4; ++i) {
    gload16(asrc[i], (unsigned short*)(smem + dstoff[i]));
    gload16(bsrc[i], (unsigned short*)(smem + 32768 + dstoff[i]));
  }
  __syncthreads();

#pragma unroll
  for (int kt = 0; kt < 6; ++kt) {
    const int cur = kt & 1;
    if (kt < 5) {
      const int nb = (cur ^ 1) * 16384;
#pragma unroll
      for (int i = 0; i < 4; ++i) {
        gload16(asrc[i] + (kt + 1) * 64, (unsigned short*)(smem + nb + dstoff[i]));
        gload16(bsrc[i] + (kt + 1) * 64, (unsigned short*)(smem + 32768 + nb + dstoff[i]));
      }
    }
    const char* Ab = smem + cur * 16384;
    const char* Bb = smem + 32768 + cur * 16384;
#pragma unroll
    for (int kk = 0; kk < 2; ++kk) {
      short8 a[4], b[4];
#pragma unroll
      for (int f = 0; f < 4; ++f) {
        a[f] = *reinterpret_cast<const short8*>(
            Ab + (wm * 64 + f * 16 + lr) * 128 + ((kk * 64 + lg * 16) ^ rxor));
        b[f] = *reinterpret_cast<const short8*>(
            Bb + (wn * 64 + f * 16 + lr) * 128 + ((kk * 64 + lg * 16) ^ rxor));
      }
#pragma unroll
      for (int mf = 0; mf < 4; ++mf)
#pragma unroll
        for (int nf = 0; nf < 4; ++nf)
          acc[mf][nf] = MFMA16(a[mf], b[nf], acc[mf][nf]);
    }
    __syncthreads();  // vmcnt(0) drain: next buffer staged; cur free for rewrite
  }

#pragma unroll
  for (int nf = 0; nf < 4; ++nf) {
    const int e = n0 + wn * 64 + nf * 16 + lr;         // 0..1151
    const float bv = bias[e];
    const int which = e / 384;                          // 0=q 1=k 2=v (wave-uniform)
    const int d = e - which * 384;
    const int h = d >> 6, hi = d & 63;
#pragma unroll
    for (int mf = 0; mf < 4; ++mf) {
      const int mm0 = m0 + wm * 64 + mf * 16 + lg * 4;
      const int b0 = mm0 >> 10, n_b = mm0 & 1023;
      const size_t bh = (size_t)(b0 * 6 + h);
      if (which == 2) {
        const int np = (n_b & ~31) | ((n_b & 12) << 1) | ((n_b & 16) >> 2);
        ushort4 sv;
        sv.x = f2bf(acc[mf][nf][0] + bv);
        sv.y = f2bf(acc[mf][nf][1] + bv);
        sv.z = f2bf(acc[mf][nf][2] + bv);
        sv.w = f2bf(acc[mf][nf][3] + bv);
        *reinterpret_cast<ushort4*>(&vt[bh * 65536 + (size_t)hi * 1024 + np]) = sv;
      } else {
        unsigned short* dst = (which == 0) ? qb : kb;
#pragma unroll
        for (int j = 0; j < 4; ++j) {
          float val = acc[mf][nf][j] + bv;
          if (which == 0) val *= 0.125f;
          dst[bh * 65536 + (size_t)(n_b + j) * 64 + hi] = f2bf(val);
        }
      }
    }
  }
}

// ---------------- flash attention (unchanged from R6) ----------------
__global__ __launch_bounds__(256, 6) void attn(
    const unsigned short* __restrict__ qb,
    const unsigned short* __restrict__ kb,
    const unsigned short* __restrict__ vt,
    unsigned short* __restrict__ ab) {
  __shared__ alignas(16) char smem[16384];  // [2][4KB K] then [2][4KB V]
  const int tid = threadIdx.x;
  const int wg = (blockIdx.x & 7) * 192 + (blockIdx.x >> 3);  // XCD swizzle
  const int bh = wg >> 4, qt = wg & 15;
  const int lane = tid & 63, wid = tid >> 6;
  const int lr = lane & 15, lg = lane >> 4;
  const size_t base = (size_t)bh * 65536;
  const unsigned short* qp = qb + base;
  const unsigned short* kp = kb + base;
  const unsigned short* vp = vt + base;
  const int q0 = qt * 64 + wid * 16;

  short8 aq0 = *reinterpret_cast<const short8*>(&qp[(size_t)(q0 + lr) * 64 + lg * 8]);
  short8 aq1 = *reinterpret_cast<const short8*>(&qp[(size_t)(q0 + lr) * 64 + 32 + lg * 8]);

  const int rK = tid >> 3;
  const int cK = (((tid & 7) * 16) ^ ((rK & 7) << 4)) >> 1;
  const int rV = tid >> 2;
  const int cV = (((tid & 3) * 16) ^ ((rV & 3) << 4)) >> 1;
  const unsigned short* ksrc = kp + rK * 64 + cK;
  const unsigned short* vsrc = vp + rV * 1024 + cV;
  unsigned short* kdst0 = (unsigned short*)(smem + wid * 1024);
  unsigned short* vdst0 = (unsigned short*)(smem + 8192 + wid * 1024);

  const int kxor = (lr & 7) << 4;
  const int vxor = (lr & 3) << 4;

  float lsum = 0.f;
  float4_t o[4] = {};

  gload16(ksrc, kdst0);
  gload16(vsrc, vdst0);
  __syncthreads();

  for (int kt = 0; kt < 32; ++kt) {
    const int cur = kt & 1;
    if (kt < 31) {
      const int nb = (cur ^ 1) * 4096;
      gload16(ksrc + (kt + 1) * 2048, (unsigned short*)((char*)kdst0 + nb));
      gload16(vsrc + (kt + 1) * 32, (unsigned short*)((char*)vdst0 + nb));
    }
    const char* kbase = smem + cur * 4096;
    const char* vbase = smem + 8192 + cur * 4096;

    short8 bk[2][2], bv[4];
#pragma unroll
    for (int kf = 0; kf < 2; ++kf)
#pragma unroll
      for (int h = 0; h < 2; ++h)
        bk[kf][h] = *reinterpret_cast<const short8*>(
            kbase + (kf * 16 + lr) * 128 + ((h * 64 + lg * 16) ^ kxor));
#pragma unroll
    for (int f = 0; f < 4; ++f)
      bv[f] = *reinterpret_cast<const short8*>(
          vbase + (f * 16 + lr) * 64 + ((lg * 16) ^ vxor));

    float4_t s[2] = {};
#pragma unroll
    for (int kf = 0; kf < 2; ++kf) {
      s[kf] = MFMA16(bk[kf][0], aq0, s[kf]);
      s[kf] = MFMA16(bk[kf][1], aq1, s[kf]);
    }
    unsigned int dw[4];
#pragma unroll
    for (int kf = 0; kf < 2; ++kf) {
      const float p0 = __expf(s[kf][0]);
      const float p1 = __expf(s[kf][1]);
      const float p2 = __expf(s[kf][2]);
      const float p3 = __expf(s[kf][3]);
      lsum += (p0 + p1) + (p2 + p3);
      dw[kf * 2]     = (unsigned int)f2bf(p0) | ((unsigned int)f2bf(p1) << 16);
      dw[kf * 2 + 1] = (unsigned int)f2bf(p2) | ((unsigned int)f2bf(p3) << 16);
    }
    uint4_t pw;
    pw[0] = dw[0]; pw[1] = dw[1]; pw[2] = dw[2]; pw[3] = dw[3];
    const short8 pa = __builtin_bit_cast(short8, pw);
#pragma unroll
    for (int f = 0; f < 4; ++f)
      o[f] = MFMA16(pa, bv[f], o[f]);

    __syncthreads();
  }

  float t = lsum;
  t += __shfl_xor(t, 16);
  t += __shfl_xor(t, 32);
  const float inv = 1.f / t;

  const int b = bh / 6, h = bh - b * 6;
  float invj[4];
#pragma unroll
  for (int j = 0; j < 4; ++j)
    invj[j] = __shfl(inv, lg * 4 + j);
#pragma unroll
  for (int f = 0; f < 4; ++f)
#pragma unroll
    for (int j = 0; j < 4; ++j) {
      const int q = q0 + lg * 4 + j;
      ab[(size_t)(b * 1024 + q) * 384 + h * 64 + f * 16 + lr] =
          f2bf(o[f][j] * invj[j]);
    }
}

// ---------------- proj GEMM v2: (16384x384)@(384x384)+bias -> fp32 ----------------
// 64x128 tile, BK=64, same staging template; grid 768 = 3 blocks/CU.
__global__ __launch_bounds__(256, 3) void gemm_proj(
    const unsigned short* __restrict__ ab,
    const unsigned short* __restrict__ wT,
    const float* __restrict__ bias,
    float* __restrict__ out) {
  __shared__ alignas(16) char smem[49152];  // A:2x8KB @0, B:2x16KB @16384
  const int tid = threadIdx.x;
  const int wg = (blockIdx.x & 7) * 96 + (blockIdx.x >> 3);  // XCD: 32 bm x 3 bn
  const int bm = wg / 3, bn = wg - bm * 3;
  const int m0 = bm * 64, n0 = bn * 128;
  const int lane = tid & 63, wid = tid >> 6;
  const int lr = lane & 15, lg = lane >> 4;
  const int wm = wid >> 1, wn = wid & 1;
  float4_t acc[2][4] = {};

  const unsigned short* asrc[2];
  const unsigned short* bsrc[4];
  int adst[2], bdst[4];
#pragma unroll
  for (int i = 0; i < 2; ++i) {
    const int idx = tid + i * 256;
    const int r = idx >> 3, c8 = idx & 7;
    asrc[i] = ab + (size_t)(m0 + r) * 384 + (c8 ^ (r & 7)) * 8;
    adst[i] = idx * 16;
  }
#pragma unroll
  for (int i = 0; i < 4; ++i) {
    const int idx = tid + i * 256;
    const int r = idx >> 3, c8 = idx & 7;
    bsrc[i] = wT + (size_t)(n0 + r) * 384 + (c8 ^ (r & 7)) * 8;
    bdst[i] = idx * 16;
  }
  const int rxor = (lr & 7) << 4;

#pragma unroll
  for (int i = 0; i < 2; ++i) gload16(asrc[i], (unsigned short*)(smem + adst[i]));
#pragma unroll
  for (int i = 0; i < 4; ++i) gload16(bsrc[i], (unsigned short*)(smem + 16384 + bdst[i]));
  __syncthreads();

#pragma unroll
  for (int kt = 0; kt < 6; ++kt) {
    const int cur = kt & 1;
    if (kt < 5) {
#pragma unroll
      for (int i = 0; i < 2; ++i)
        gload16(asrc[i] + (kt + 1) * 64, (unsigned short*)(smem + (cur ^ 1) * 8192 + adst[i]));
#pragma unroll
      for (int i = 0; i < 4; ++i)
        gload16(bsrc[i] + (kt + 1) * 64, (unsigned short*)(smem + 16384 + (cur ^ 1) * 16384 + bdst[i]));
    }
    const char* Ab = smem + cur * 8192;
    const char* Bb = smem + 16384 + cur * 16384;
#pragma unroll
    for (int kk = 0; kk < 2; ++kk) {
      short8 a[2], b[4];
#pragma unroll
      for (int f = 0; f < 2; ++f)
        a[f] = *reinterpret_cast<const short8*>(
            Ab + (wm * 32 + f * 16 + lr) * 128 + ((kk * 64 + lg * 16) ^ rxor));
#pragma unroll
      for (int f = 0; f < 4; ++f)
        b[f] = *reinterpret_cast<const short8*>(
            Bb + (wn * 64 + f * 16 + lr) * 128 + ((kk * 64 + lg * 16) ^ rxor));
#pragma unroll
      for (int mf = 0; mf < 2; ++mf)
#pragma unroll
        for (int nf = 0; nf < 4; ++nf)
          acc[mf][nf] = MFMA16(a[mf], b[nf], acc[mf][nf]);
    }
    __syncthreads();
  }

#pragma unroll
  for (int nf = 0; nf < 4; ++nf) {
    const int e = n0 + wn * 64 + nf * 16 + lr;  // < 384
    const float bv = bias[e];
#pragma unroll
    for (int mf = 0; mf < 2; ++mf) {
#pragma unroll
      for (int j = 0; j < 4; ++j) {
        const int mm = m0 + wm * 32 + mf * 16 + lg * 4 + j;
        out[(size_t)mm * 384 + e] = acc[mf][nf][j] + bv;
      }
    }
  }
}

extern "C" void kernel_launch(void* const* d_in, const int* in_sizes, int n_in,
                              void* d_out, int out_size, void* d_ws, size_t ws_size,
                              hipStream_t stream) {
  const float* x      = (const float*)d_in[0];
  const float* w_qkv  = (const float*)d_in[1];
  const float* b_qkv  = (const float*)d_in[2];
  const float* w_proj = (const float*)d_in[3];
  const float* b_proj = (const float*)d_in[4];
  float* out = (float*)d_out;

  char* ws = (char*)d_ws;
  unsigned short* xb     = (unsigned short*)(ws);               // 12,582,912 B
  unsigned short* wqkvT  = (unsigned short*)(ws + 12582912);    //    884,736 B
  unsigned short* wprojT = (unsigned short*)(ws + 13467648);    //    294,912 B
  unsigned short* qb     = (unsigned short*)(ws + 13762560);    // 12,582,912 B
  unsigned short* kb     = (unsigned short*)(ws + 26345472);    // 12,582,912 B
  unsigned short* vt     = (unsigned short*)(ws + 38928384);    // 12,582,912 B
  unsigned short* ab     = xb;  // xb is dead after gemm_qkv; reuse for attn out

  prep<<<6720, 256, 0, stream>>>(x, w_qkv, w_proj, xb, wqkvT, wprojT);
  gemm_qkv<<<1152, 256, 0, stream>>>(xb, wqkvT, b_qkv, qb, kb, vt);
  attn<<<1536, 256, 0, stream>>>(qb, kb, vt, ab);
  gemm_proj<<<768, 256, 0, stream>>>(ab, wprojT, b_proj, out);
}

// Round 9
// 87.172 us; speedup vs baseline: 1.9742x; 1.1025x over previous
//
#include <hip/hip_runtime.h>

typedef __attribute__((ext_vector_type(8))) short short8;
typedef __attribute__((ext_vector_type(4))) float float4_t;
typedef __attribute__((ext_vector_type(4))) unsigned int uint4_t;

#define MFMA16(A, B, C) __builtin_amdgcn_mfma_f32_16x16x32_bf16(A, B, C, 0, 0, 0)

// softmax scale * log2(e), folded into Q at QKV-epilogue time (fp32 multiply,
// single bf16 rounding -> same error structure as plain 0.125 scale)
#define QSCALE 0.1803368801111168f

__device__ __forceinline__ unsigned short f2bf(float f) {
  unsigned int u = __builtin_bit_cast(unsigned int, f);
  u += 0x7FFFu + ((u >> 16) & 1u);   // RNE
  return (unsigned short)(u >> 16);
}

__device__ __forceinline__ void gload16(const unsigned short* g, unsigned short* l) {
  __builtin_amdgcn_global_load_lds(
      (const __attribute__((address_space(1))) unsigned int*)(g),
      (__attribute__((address_space(3))) unsigned int*)(l), 16, 0, 0);
}

// ---------------- prep: x->bf16 cvt + both weight transposes ----------------
__global__ __launch_bounds__(256) void prep(
    const float* __restrict__ x, const float* __restrict__ w_qkv,
    const float* __restrict__ w_proj, unsigned short* __restrict__ xb,
    unsigned short* __restrict__ wqkvT, unsigned short* __restrict__ wprojT) {
  __shared__ unsigned short tile[32][33];
  const int bid = blockIdx.x, tid = threadIdx.x;
  if (bid < 6144) {
    const int i = bid * 256 + tid;
    float4 v = reinterpret_cast<const float4*>(x)[i];
    ushort4 r;
    r.x = f2bf(v.x); r.y = f2bf(v.y); r.z = f2bf(v.z); r.w = f2bf(v.w);
    reinterpret_cast<ushort4*>(xb)[i] = r;
    return;
  }
  const float* w; unsigned short* wT; int E, t;
  if (bid < 6576) { t = bid - 6144; w = w_qkv; wT = wqkvT; E = 1152; }
  else            { t = bid - 6576; w = w_proj; wT = wprojT; E = 384; }
  const int tiles_e = E >> 5;
  const int td = t / tiles_e, te = t - td * tiles_e;
  const int r = tid >> 3, c4 = (tid & 7) * 4;
  float4 v = *reinterpret_cast<const float4*>(&w[(size_t)(td * 32 + r) * E + te * 32 + c4]);
  tile[r][c4 + 0] = f2bf(v.x);
  tile[r][c4 + 1] = f2bf(v.y);
  tile[r][c4 + 2] = f2bf(v.z);
  tile[r][c4 + 3] = f2bf(v.w);
  __syncthreads();
  ushort4 o;
  o.x = tile[c4 + 0][r]; o.y = tile[c4 + 1][r];
  o.z = tile[c4 + 2][r]; o.w = tile[c4 + 3][r];
  *reinterpret_cast<ushort4*>(&wT[(size_t)(te * 32 + r) * 384 + td * 32 + c4]) = o;
}

// ---------------- QKV GEMM: (16384x384)@(384x1152)+bias ----------------
// q/k blocks (bn<6) use SWAPPED mfma operands (D: row=feature, col=token) so
// each lane holds 4 consecutive features of one token -> ushort4 stores.
// v blocks (bn>=6) keep the original order (np-permuted store already vec4).
__global__ __launch_bounds__(256, 2) void gemm_qkv(
    const unsigned short* __restrict__ xb,
    const unsigned short* __restrict__ wT,
    const float* __restrict__ bias,
    unsigned short* __restrict__ qb,
    unsigned short* __restrict__ kb,
    unsigned short* __restrict__ vt) {
  __shared__ alignas(16) char smem[65536];  // A:2x16KB @0, B:2x16KB @32768
  const int tid = threadIdx.x;
  const int wg = (blockIdx.x & 7) * 144 + (blockIdx.x >> 3);
  const int bm = wg / 9, bn = wg - bm * 9;
  const int m0 = bm * 128, n0 = bn * 128;
  const int lane = tid & 63, wid = tid >> 6;
  const int lr = lane & 15, lg = lane >> 4;
  const int wm = wid >> 1, wn = wid & 1;
  float4_t acc[4][4] = {};

  const unsigned short* asrc[4];
  const unsigned short* bsrc[4];
  int dstoff[4];
#pragma unroll
  for (int i = 0; i < 4; ++i) {
    const int idx = tid + i * 256;
    const int r = idx >> 3, c8 = idx & 7;
    const int cc = (c8 ^ (r & 7)) * 8;
    asrc[i] = xb + (size_t)(m0 + r) * 384 + cc;
    bsrc[i] = wT + (size_t)(n0 + r) * 384 + cc;
    dstoff[i] = idx * 16;
  }
  const int rxor = (lr & 7) << 4;

#pragma unroll
  for (int i = 0; i < 4; ++i) {
    gload16(asrc[i], (unsigned short*)(smem + dstoff[i]));
    gload16(bsrc[i], (unsigned short*)(smem + 32768 + dstoff[i]));
  }
  __syncthreads();

#pragma unroll
  for (int kt = 0; kt < 6; ++kt) {
    const int cur = kt & 1;
    if (kt < 5) {
      const int nb = (cur ^ 1) * 16384;
#pragma unroll
      for (int i = 0; i < 4; ++i) {
        gload16(asrc[i] + (kt + 1) * 64, (unsigned short*)(smem + nb + dstoff[i]));
        gload16(bsrc[i] + (kt + 1) * 64, (unsigned short*)(smem + 32768 + nb + dstoff[i]));
      }
    }
    const char* Ab = smem + cur * 16384;
    const char* Bb = smem + 32768 + cur * 16384;
#pragma unroll
    for (int kk = 0; kk < 2; ++kk) {
      short8 a[4], b[4];
#pragma unroll
      for (int f = 0; f < 4; ++f) {
        a[f] = *reinterpret_cast<const short8*>(
            Ab + (wm * 64 + f * 16 + lr) * 128 + ((kk * 64 + lg * 16) ^ rxor));
        b[f] = *reinterpret_cast<const short8*>(
            Bb + (wn * 64 + f * 16 + lr) * 128 + ((kk * 64 + lg * 16) ^ rxor));
      }
      if (bn < 6) {
#pragma unroll
        for (int mf = 0; mf < 4; ++mf)
#pragma unroll
          for (int nf = 0; nf < 4; ++nf)
            acc[mf][nf] = MFMA16(b[nf], a[mf], acc[mf][nf]);  // swapped
      } else {
#pragma unroll
        for (int mf = 0; mf < 4; ++mf)
#pragma unroll
          for (int nf = 0; nf < 4; ++nf)
            acc[mf][nf] = MFMA16(a[mf], b[nf], acc[mf][nf]);
      }
    }
    __syncthreads();
  }

  if (bn < 6) {
    // q/k: lane holds 4 consecutive features (lg*4+j) of token (.. + lr)
    const int whichk = (bn >= 3);
    unsigned short* dst = whichk ? kb : qb;
    const float sc = whichk ? 1.f : QSCALE;
#pragma unroll
    for (int nf = 0; nf < 4; ++nf) {
      const int e0 = n0 + wn * 64 + nf * 16 + lg * 4;
      const int d0 = e0 - whichk * 384;
      const int h = d0 >> 6, hi0 = d0 & 63;
      const float4 bv4 = *reinterpret_cast<const float4*>(&bias[e0]);
#pragma unroll
      for (int mf = 0; mf < 4; ++mf) {
        const int mm = m0 + wm * 64 + mf * 16 + lr;
        const int b0 = mm >> 10, n_b = mm & 1023;
        const size_t bhh = (size_t)(b0 * 6 + h);
        ushort4 sv;
        sv.x = f2bf((acc[mf][nf][0] + bv4.x) * sc);
        sv.y = f2bf((acc[mf][nf][1] + bv4.y) * sc);
        sv.z = f2bf((acc[mf][nf][2] + bv4.z) * sc);
        sv.w = f2bf((acc[mf][nf][3] + bv4.w) * sc);
        *reinterpret_cast<ushort4*>(&dst[bhh * 65536 + (size_t)n_b * 64 + hi0]) = sv;
      }
    }
  } else {
    // v: original fragment (row=token, col=feature), np-permuted vec4 store
#pragma unroll
    for (int nf = 0; nf < 4; ++nf) {
      const int e = n0 + wn * 64 + nf * 16 + lr;   // [768,1152)
      const float bv = bias[e];
      const int d = e - 768;
      const int h = d >> 6, hi = d & 63;
#pragma unroll
      for (int mf = 0; mf < 4; ++mf) {
        const int mm0 = m0 + wm * 64 + mf * 16 + lg * 4;
        const int b0 = mm0 >> 10, n_b = mm0 & 1023;
        const size_t bhh = (size_t)(b0 * 6 + h);
        const int np = (n_b & ~31) | ((n_b & 12) << 1) | ((n_b & 16) >> 2);
        ushort4 sv;
        sv.x = f2bf(acc[mf][nf][0] + bv);
        sv.y = f2bf(acc[mf][nf][1] + bv);
        sv.z = f2bf(acc[mf][nf][2] + bv);
        sv.w = f2bf(acc[mf][nf][3] + bv);
        *reinterpret_cast<ushort4*>(&vt[bhh * 65536 + (size_t)hi * 1024 + np]) = sv;
      }
    }
  }
}

// ---------------- flash attention v4: KVBLK=64, 8 waves, exp2+cvt_pk ----------------
// grid = 96 (b,h) x 8 q-tiles of 128; 8 waves x 16 queries; 3 blocks/CU.
// K/V staged once per block into double-buffered LDS (128B rows, 8-slot XOR
// swizzle -> conflict-free). Softmax: s is in log2 units (QSCALE pre-folded),
// p = v_exp_f32(s); P packed via v_cvt_pk_bf16_f32 (truncating) and lsum
// accumulates the UNPACKED truncated values -> numerator/denominator
// consistent, truncation bias cancels exactly.
__global__ __launch_bounds__(512, 6) void attn(
    const unsigned short* __restrict__ qb,
    const unsigned short* __restrict__ kb,
    const unsigned short* __restrict__ vt,
    unsigned short* __restrict__ ab) {
  __shared__ alignas(16) char smem[32768];  // K:[2][8KB] @0, V:[2][8KB] @16384
  const int tid = threadIdx.x;
  const int wg = (blockIdx.x & 7) * 96 + (blockIdx.x >> 3);  // XCD swizzle
  const int bh = wg >> 3, qt = wg & 7;
  const int lane = tid & 63, wid = tid >> 6;
  const int lr = lane & 15, lg = lane >> 4;
  const size_t base = (size_t)bh * 65536;
  const unsigned short* qp = qb + base;
  const unsigned short* kp = kb + base;
  const unsigned short* vp = vt + base;
  const int q0 = qt * 128 + wid * 16;

  short8 aq0 = *reinterpret_cast<const short8*>(&qp[(size_t)(q0 + lr) * 64 + lg * 8]);
  short8 aq1 = *reinterpret_cast<const short8*>(&qp[(size_t)(q0 + lr) * 64 + 32 + lg * 8]);

  // staging sources (inverse-swizzled): 512 thr x 16B = 8KB per tile each
  const int rr = tid >> 3;
  const int cc = (((tid & 7) * 16) ^ ((rr & 7) << 4)) >> 1;  // elements
  const unsigned short* ksrc = kp + rr * 64 + cc;            // + kt*4096
  const unsigned short* vsrc = vp + rr * 1024 + cc;          // + kt*64
  unsigned short* kdst = (unsigned short*)(smem + tid * 16);
  unsigned short* vdst = (unsigned short*)(smem + 16384 + tid * 16);

  const int xr = (lr & 7) << 4;

  float lsum = 0.f;
  float4_t o[4] = {};

  gload16(ksrc, kdst);
  gload16(vsrc, vdst);
  __syncthreads();

  for (int kt = 0; kt < 16; ++kt) {
    const int cur = kt & 1;
    if (kt < 15) {
      const int nb = (cur ^ 1) * 8192;
      gload16(ksrc + (kt + 1) * 4096, (unsigned short*)(smem + nb + tid * 16));
      gload16(vsrc + (kt + 1) * 64, (unsigned short*)(smem + 16384 + nb + tid * 16));
    }
    const char* kbase = smem + cur * 8192;
    const char* vbase = smem + 16384 + cur * 8192;

#pragma unroll
    for (int half = 0; half < 2; ++half) {
      short8 bk00 = *reinterpret_cast<const short8*>(
          kbase + (half * 32 + lr) * 128 + ((lg * 16) ^ xr));
      short8 bk01 = *reinterpret_cast<const short8*>(
          kbase + (half * 32 + lr) * 128 + ((64 + lg * 16) ^ xr));
      short8 bk10 = *reinterpret_cast<const short8*>(
          kbase + (half * 32 + 16 + lr) * 128 + ((lg * 16) ^ xr));
      short8 bk11 = *reinterpret_cast<const short8*>(
          kbase + (half * 32 + 16 + lr) * 128 + ((64 + lg * 16) ^ xr));
      float4_t s0 = {}, s1 = {};
      s0 = MFMA16(bk00, aq0, s0);
      s0 = MFMA16(bk01, aq1, s0);
      s1 = MFMA16(bk10, aq0, s1);
      s1 = MFMA16(bk11, aq1, s1);

      unsigned int dw0, dw1, dw2, dw3;
      {
        const float p0 = __builtin_amdgcn_exp2f(s0[0]);
        const float p1 = __builtin_amdgcn_exp2f(s0[1]);
        const float p2 = __builtin_amdgcn_exp2f(s0[2]);
        const float p3 = __builtin_amdgcn_exp2f(s0[3]);
        asm("v_cvt_pk_bf16_f32 %0, %1, %2" : "=v"(dw0) : "v"(p0), "v"(p1));
        asm("v_cvt_pk_bf16_f32 %0, %1, %2" : "=v"(dw1) : "v"(p2), "v"(p3));
        const float p4 = __builtin_amdgcn_exp2f(s1[0]);
        const float p5 = __builtin_amdgcn_exp2f(s1[1]);
        const float p6 = __builtin_amdgcn_exp2f(s1[2]);
        const float p7 = __builtin_amdgcn_exp2f(s1[3]);
        asm("v_cvt_pk_bf16_f32 %0, %1, %2" : "=v"(dw2) : "v"(p4), "v"(p5));
        asm("v_cvt_pk_bf16_f32 %0, %1, %2" : "=v"(dw3) : "v"(p6), "v"(p7));
      }
      // consistent denominator: sum the truncated bf16 values actually used
      lsum += __builtin_bit_cast(float, dw0 << 16) +
              __builtin_bit_cast(float, dw0 & 0xFFFF0000u) +
              __builtin_bit_cast(float, dw1 << 16) +
              __builtin_bit_cast(float, dw1 & 0xFFFF0000u) +
              __builtin_bit_cast(float, dw2 << 16) +
              __builtin_bit_cast(float, dw2 & 0xFFFF0000u) +
              __builtin_bit_cast(float, dw3 << 16) +
              __builtin_bit_cast(float, dw3 & 0xFFFF0000u);

      uint4_t pw;
      pw[0] = dw0; pw[1] = dw1; pw[2] = dw2; pw[3] = dw3;
      const short8 pa = __builtin_bit_cast(short8, pw);
#pragma unroll
      for (int f = 0; f < 4; ++f) {
        short8 bv = *reinterpret_cast<const short8*>(
            vbase + (f * 16 + lr) * 128 + ((half * 64 + lg * 16) ^ xr));
        o[f] = MFMA16(pa, bv, o[f]);
      }
    }
    __syncthreads();
  }

  float t = lsum;
  t += __shfl_xor(t, 16);
  t += __shfl_xor(t, 32);
  const float inv = 1.f / t;

  const int b = bh / 6, h = bh - b * 6;
  float invj[4];
#pragma unroll
  for (int j = 0; j < 4; ++j)
    invj[j] = __shfl(inv, lg * 4 + j);
#pragma unroll
  for (int f = 0; f < 4; ++f)
#pragma unroll
    for (int j = 0; j < 4; ++j) {
      const int q = q0 + lg * 4 + j;
      ab[(size_t)(b * 1024 + q) * 384 + h * 64 + f * 16 + lr] =
          f2bf(o[f][j] * invj[j]);
    }
}

// ---------------- proj GEMM: (16384x384)@(384x384)+bias -> fp32 ----------------
// Swapped operands: lane holds 4 consecutive features -> float4 stores.
__global__ __launch_bounds__(256, 3) void gemm_proj(
    const unsigned short* __restrict__ ab,
    const unsigned short* __restrict__ wT,
    const float* __restrict__ bias,
    float* __restrict__ out) {
  __shared__ alignas(16) char smem[49152];  // A:2x8KB @0, B:2x16KB @16384
  const int tid = threadIdx.x;
  const int wg = (blockIdx.x & 7) * 96 + (blockIdx.x >> 3);
  const int bm = wg / 3, bn = wg - bm * 3;
  const int m0 = bm * 64, n0 = bn * 128;
  const int lane = tid & 63, wid = tid >> 6;
  const int lr = lane & 15, lg = lane >> 4;
  const int wm = wid >> 1, wn = wid & 1;
  float4_t acc[2][4] = {};

  const unsigned short* asrc[2];
  const unsigned short* bsrc[4];
  int adst[2], bdst[4];
#pragma unroll
  for (int i = 0; i < 2; ++i) {
    const int idx = tid + i * 256;
    const int r = idx >> 3, c8 = idx & 7;
    asrc[i] = ab + (size_t)(m0 + r) * 384 + (c8 ^ (r & 7)) * 8;
    adst[i] = idx * 16;
  }
#pragma unroll
  for (int i = 0; i < 4; ++i) {
    const int idx = tid + i * 256;
    const int r = idx >> 3, c8 = idx & 7;
    bsrc[i] = wT + (size_t)(n0 + r) * 384 + (c8 ^ (r & 7)) * 8;
    bdst[i] = idx * 16;
  }
  const int rxor = (lr & 7) << 4;

#pragma unroll
  for (int i = 0; i < 2; ++i) gload16(asrc[i], (unsigned short*)(smem + adst[i]));
#pragma unroll
  for (int i = 0; i < 4; ++i) gload16(bsrc[i], (unsigned short*)(smem + 16384 + bdst[i]));
  __syncthreads();

#pragma unroll
  for (int kt = 0; kt < 6; ++kt) {
    const int cur = kt & 1;
    if (kt < 5) {
#pragma unroll
      for (int i = 0; i < 2; ++i)
        gload16(asrc[i] + (kt + 1) * 64, (unsigned short*)(smem + (cur ^ 1) * 8192 + adst[i]));
#pragma unroll
      for (int i = 0; i < 4; ++i)
        gload16(bsrc[i] + (kt + 1) * 64, (unsigned short*)(smem + 16384 + (cur ^ 1) * 16384 + bdst[i]));
    }
    const char* Ab = smem + cur * 8192;
    const char* Bb = smem + 16384 + cur * 16384;
#pragma unroll
    for (int kk = 0; kk < 2; ++kk) {
      short8 a[2], b[4];
#pragma unroll
      for (int f = 0; f < 2; ++f)
        a[f] = *reinterpret_cast<const short8*>(
            Ab + (wm * 32 + f * 16 + lr) * 128 + ((kk * 64 + lg * 16) ^ rxor));
#pragma unroll
      for (int f = 0; f < 4; ++f)
        b[f] = *reinterpret_cast<const short8*>(
            Bb + (wn * 64 + f * 16 + lr) * 128 + ((kk * 64 + lg * 16) ^ rxor));
#pragma unroll
      for (int mf = 0; mf < 2; ++mf)
#pragma unroll
        for (int nf = 0; nf < 4; ++nf)
          acc[mf][nf] = MFMA16(b[nf], a[mf], acc[mf][nf]);  // swapped
    }
    __syncthreads();
  }

#pragma unroll
  for (int nf = 0; nf < 4; ++nf) {
    const int e0 = n0 + wn * 64 + nf * 16 + lg * 4;
    const float4 bv4 = *reinterpret_cast<const float4*>(&bias[e0]);
#pragma unroll
    for (int mf = 0; mf < 2; ++mf) {
      const int mm = m0 + wm * 32 + mf * 16 + lr;
      float4 ov;
      ov.x = acc[mf][nf][0] + bv4.x;
      ov.y = acc[mf][nf][1] + bv4.y;
      ov.z = acc[mf][nf][2] + bv4.z;
      ov.w = acc[mf][nf][3] + bv4.w;
      *reinterpret_cast<float4*>(&out[(size_t)mm * 384 + e0]) = ov;
    }
  }
}

extern "C" void kernel_launch(void* const* d_in, const int* in_sizes, int n_in,
                              void* d_out, int out_size, void* d_ws, size_t ws_size,
                              hipStream_t stream) {
  const float* x      = (const float*)d_in[0];
  const float* w_qkv  = (const float*)d_in[1];
  const float* b_qkv  = (const float*)d_in[2];
  const float* w_proj = (const float*)d_in[3];
  const float* b_proj = (const float*)d_in[4];
  float* out = (float*)d_out;

  char* ws = (char*)d_ws;
  unsigned short* xb     = (unsigned short*)(ws);               // 12,582,912 B
  unsigned short* wqkvT  = (unsigned short*)(ws + 12582912);    //    884,736 B
  unsigned short* wprojT = (unsigned short*)(ws + 13467648);    //    294,912 B
  unsigned short* qb     = (unsigned short*)(ws + 13762560);    // 12,582,912 B
  unsigned short* kb     = (unsigned short*)(ws + 26345472);    // 12,582,912 B
  unsigned short* vt     = (unsigned short*)(ws + 38928384);    // 12,582,912 B
  unsigned short* ab     = xb;  // xb is dead after gemm_qkv; reuse for attn out

  prep<<<6720, 256, 0, stream>>>(x, w_qkv, w_proj, xb, wqkvT, wprojT);
  gemm_qkv<<<1152, 256, 0, stream>>>(xb, wqkvT, b_qkv, qb, kb, vt);
  attn<<<768, 512, 0, stream>>>(qb, kb, vt, ab);
  gemm_proj<<<768, 256, 0, stream>>>(ab, wprojT, b_proj, out);
}